// Round 11
// baseline (426.402 us; speedup 1.0000x reference)
//
#include <hip/hip_runtime.h>

#define T_LEN 512
#define HID   40
#define BT    8        // sequences per block -> grid 256 = 1 block/CU
#define NTH   640      // 10 waves; wave w owns units u = 4w..4w+3 (all 4 gates)

typedef _Float16 f16x8 __attribute__((ext_vector_type(8)));
typedef float    f32x4 __attribute__((ext_vector_type(4)));
typedef float    f32x2 __attribute__((ext_vector_type(2)));

// Unified B-buffer per parity: ONE chunked K-axis
//   [h0: gk 0..39 | x: 40..45 | h1: 46..85 | h2: 86..125 | pad: 126..127]
// = 128 chunks x 16 cols. Cols 0-7 = the 8 sequences; cols 8-15 are ZERO.
// All three gemms read phase-aligned 32-gk windows r0..r3 (4 x ds_read_b128).
// A-side: fp16 hi only. MFMA chains stay D=C chained (rounds 1/7: splitting
// a chain adds full MFMA->VALU hazard windows; C-accumulation is near-free).
// MFMA count 8 is the window floor (ceil(46/32)+ceil(80/32)+ceil(80/32));
// trans count 8 evals is the lane-pair floor; 1 barrier/timestep structural.
#define PARSZ 2048     // fp16 per parity (256 chunks * 8); 2 parities = 8 KB

#define NLOG2E  (-1.4426950408889634f)   // -log2(e): sigmoid-gate pre-scale
#define N2LOG2E (-2.8853900817779268f)   // -2*log2(e): tanh-gate pre-scale

__device__ __forceinline__ float fast_rcp(float v)  { return __builtin_amdgcn_rcpf(v); }
__device__ __forceinline__ float fast_exp2(float v) { return __builtin_amdgcn_exp2f(v); }

__device__ __forceinline__ float dpp_add_xor1(float x) {
    return x + __int_as_float(__builtin_amdgcn_update_dpp(
                   0, __float_as_int(x), 0xB1, 0xF, 0xF, true));
}
__device__ __forceinline__ float dpp_add_xor2(float x) {
    return x + __int_as_float(__builtin_amdgcn_update_dpp(
                   0, __float_as_int(x), 0x4E, 0xF, 0xF, true));
}
// row_ror:8 — lane n receives lane (n+8)%16 of its 16-lane row. Pure VALU.
__device__ __forceinline__ float dpp_mov_ror8(float x) {
    return __int_as_float(__builtin_amdgcn_update_dpp(
               0, __float_as_int(x), 0x128, 0xF, 0xF, true));
}
// masked ror8-select: lanes 0-7 of each row keep `keep`; lanes 8-15 receive
// `src` from lane (n+8)%16 (their hi partner). One v_mov_b32_dpp.
__device__ __forceinline__ float dpp_sel_ror8(float keep, float src) {
    return __int_as_float(__builtin_amdgcn_update_dpp(
               __float_as_int(keep), __float_as_int(src), 0x128, 0xF, 0xC, false));
}

// element index for (global-k, col): chunk = (gk/32)*64 + ((gk%32)/8)*16 + col
__device__ __forceinline__ int bidx(int gk, int col) {
    return (((gk >> 5) * 64) + (((gk >> 3) & 3) * 16) + col) * 8 + (gk & 7);
}

#define MFMA16(A, B, C) __builtin_amdgcn_mfma_f32_16x16x32_f16((A), (B), (C), 0, 0, 0)

__global__ __launch_bounds__(NTH, 1) void lstm_fused(
    const float* __restrict__ x,
    const float* __restrict__ Wih0, const float* __restrict__ Whh0,
    const float* __restrict__ bih0, const float* __restrict__ bhh0,
    const float* __restrict__ Wih1, const float* __restrict__ Whh1,
    const float* __restrict__ bih1, const float* __restrict__ bhh1,
    const float* __restrict__ Wih2, const float* __restrict__ Whh2,
    const float* __restrict__ bih2, const float* __restrict__ bhh2,
    const float* __restrict__ Wout, const float* __restrict__ bout,
    float* __restrict__ out) {
    __shared__ __attribute__((aligned(16))) _Float16 sBF[2 * PARSZ];   // 8 KB
    __shared__ __attribute__((aligned(16))) float    sY[8 * HID * BT]; // 10 KB

    const int  tid  = threadIdx.x;
    const int  lane = tid & 63;
    const int  w    = tid >> 6;       // wave id = u-tile
    const int  n    = lane & 15;      // B/D column (seq b when n<8; n>=8 helper)
    const int  quad = lane >> 4;
    const int  u    = w * 4 + quad;   // hidden unit this lane owns (cell update)
    const int  seq0 = blockIdx.x * BT;
    const bool hiL  = (n < 8);        // hi-half lane?

    // ---- A-fragments: gate-permuted rows (j = (r%4)*40 + w*4 + r/4), fp16 hi,
    // pre-scaled (sigmoid x -log2e, tanh x -2log2e). One frag per
    // (gemm, window): L0 uses {r0,r1} (x folded into r1), L1 {r0,r1,r2},
    // L2 {r1,r2,r3}.
    const int   ja  = (n & 3) * 40 + w * 4 + (n >> 2);
    const float sca = ((n & 3) == 2) ? N2LOG2E : NLOG2E;
    f16x8 F0h[2], F1h[3], F2h[3];
#pragma unroll
    for (int jj = 0; jj < 8; ++jj) {
        int gk0 = quad * 8 + jj;        // r0 window: gk 0..31
        int gk1 = 32 + gk0;             // r1: gk 32..63
        int gk2 = 64 + gk0;             // r2: gk 64..95
        int gk3 = 96 + gk0;             // r3: gk 96..127
        float v;
        // L0 = Whh0*h0 + Wih0*x : support gk 0..39 (h0) and 40..45 (x)
        v = Whh0[ja * 40 + gk0] * sca;
        F0h[0][jj] = (_Float16)v;
        v = (gk1 < 40) ? Whh0[ja * 40 + gk1] * sca
          : ((gk1 < 46) ? Wih0[ja * 6 + (gk1 - 40)] * sca : 0.f);
        F0h[1][jj] = (_Float16)v;
        // L1 = Wih1*h0 + Whh1*h1 : support gk 0..39 (h0) and 46..85 (h1)
        v = Wih1[ja * 40 + gk0] * sca;
        F1h[0][jj] = (_Float16)v;
        v = (gk1 < 40) ? Wih1[ja * 40 + gk1] * sca
          : ((gk1 >= 46) ? Whh1[ja * 40 + (gk1 - 46)] * sca : 0.f);
        F1h[1][jj] = (_Float16)v;
        v = (gk2 < 86) ? Whh1[ja * 40 + (gk2 - 46)] * sca : 0.f;
        F1h[2][jj] = (_Float16)v;
        // L2 = Wih2*h1 + Whh2*h2 : support gk 46..85 (h1) and 86..125 (h2)
        v = (gk1 >= 46) ? Wih2[ja * 40 + (gk1 - 46)] * sca : 0.f;
        F2h[0][jj] = (_Float16)v;
        v = ((gk2 < 86) ? Wih2[ja * 40 + (gk2 - 46)] : Whh2[ja * 40 + (gk2 - 86)]) * sca;
        F2h[1][jj] = (_Float16)v;
        v = (gk3 < 126) ? Whh2[ja * 40 + (gk3 - 86)] * sca : 0.f;
        F2h[2][jj] = (_Float16)v;
    }

    // biases: acc-init = scale*bias (single-column B: no hi+lo fold doubling)
    f32x4 bia0, bia1, bia2;
#pragma unroll
    for (int reg = 0; reg < 4; ++reg) {
        int   jr = reg * 40 + u;
        float sc = (reg == 2) ? N2LOG2E : NLOG2E;
        bia0[reg] = sc * (bih0[jr] + bhh0[jr]);
        bia1[reg] = sc * (bih1[jr] + bhh1[jr]);
        bia2[reg] = sc * (bih2[jr] + bhh2[jr]);
    }
    const float wov   = Wout[u];
    const float boutv = bout[0];
    // per-lane sigmoid/tanh affine constants: v0 = kA*e0 + kB
    // hi: 1*e0 + 0 = sigmoid   lo: 2*e0 - 1 = tanh  (exact coefficients)
    const float kA = hiL ? 1.f : 2.f;
    const float kB = hiL ? 0.f : -1.f;
    const f32x2 one2  = {1.f, 1.f};
    const f32x2 nl2e2 = {N2LOG2E, N2LOG2E};

    float c0 = 0.f, c1 = 0.f, c2 = 0.f;  // c0 valid hi, c1 lo, c2 hi (garbage
                                         // halves bounded: fs<1, |ig|<=1, and
                                         // +-inf degrades to th=+-1, no NaN)

    // ---- loop-invariant LDS indices (elems) ----
    const int rOff = lane * 8;           // shared-window read offset
    const int iH0  = bidx(u, n);         // h0 write (gk = u), hi lanes only
    const int iH1  = bidx(46 + u, n);    // h1 (gk = 46+u)
    const int iH2  = bidx(86 + u, n);    // h2 (gk = 86+u)

    // ---- x staging on wave 2 (x lives at gk 40..45, cols 0..7 only) ----
    const bool   xact = (tid >= 128 && tid < 176);
    const int    e    = tid - 128;
    const int    xs   = e / 6, xd = e % 6;
    const int    ixi  = bidx(40 + xd, xs);
    const float* xbl  = x + ((size_t)(seq0 + xs) * T_LEN) * 6 + xd;
    float        xr   = 0.f;
    if (xact) xr = xbl[0];  // x(0)

    // zero both parity banks (pads + cols 8-15 + unwritten regions stay zero)
    for (int i = tid; i < 2 * PARSZ / 8; i += NTH)
        *(float4*)&sBF[i * 8] = make_float4(0.f, 0.f, 0.f, 0.f);
    __syncthreads();
    if (xact) {
        sBF[ixi] = (_Float16)xr;   // x(0) -> parity 0
        xr = xbl[6];               // prefetch x(1)
    }
    __syncthreads();

    // stage1: bank-masked dpp gathers the partner's g/o accs onto lo lanes in
    // one instr each; affine kA/kB folds the sig/tanh divergence into one fma;
    // the two 1+exp adds are packed (v_pk_add_f32).
    // Returns: ig (valid both halves), v1 (hi = sig(f)), r1 = ror8(v1).
    auto stage1 = [&](f32x4 acc, float& ig, float& v1o, float& r1o) {
        float in0 = dpp_sel_ror8(acc[0], acc[2]);   // hi: i-acc  lo: g-acc
        float in1 = dpp_sel_ror8(acc[1], acc[3]);   // hi: f-acc  lo: o-acc
        f32x2 ee  = {fast_exp2(in0), fast_exp2(in1)};
        f32x2 dd  = ee + one2;                      // packed 1+e
        float e0  = fast_rcp(dd[0]);
        float v1  = fast_rcp(dd[1]);                // hi: sig(f)  lo: sig(o)
        float v0  = e0 * kA + kB;                   // hi: sig(i)  lo: tanh(g)
        float r0  = dpp_mov_ror8(v0);
        ig  = v0 * r0;                              // sig(i)*tanh(g) both halves
        v1o = v1;
        r1o = dpp_mov_ror8(v1);
    };

    // lagged output flush on waves 0,1 (x duty stays on wave 2)
    auto flushY = [&](int t2g) {
        int q = tid, o = q >> 2, part = q & 3;
        int tt = o >> 3, bb = o & 7;
        int slot = (t2g + tt) & 7;
        float s = 0.f;
#pragma unroll
        for (int i2 = 0; i2 < 10; ++i2)
            s += sY[slot * (HID * BT) + (part * 10 + i2) * BT + bb];
        s = dpp_add_xor1(s);
        s = dpp_add_xor2(s);
        if (part == 0)
            out[(size_t)(seq0 + bb) * T_LEN + t2g + tt] = s + boutv;
    };

    // One pipeline interval k: L0(t=k), L1(t=k-1), L2(t=k-2). Reads P, writes Q,
    // ONE barrier. 4 shared b128 reads feed all three gemm chains (3x ILP).
    auto interval = [&](_Float16* __restrict__ P, _Float16* __restrict__ Q,
                        int k, bool a0, bool a1, bool a2) {
        f16x8 b0 = *(const f16x8*)(P + 0    + rOff);
        f16x8 b1 = *(const f16x8*)(P + 512  + rOff);
        f16x8 b2 = *(const f16x8*)(P + 1024 + rOff);
        f16x8 b3 = *(const f16x8*)(P + 1536 + rOff);

        f32x4 acc0, acc1, acc2;
        if (a0) {   // L0: K-support entirely in r0+r1 (x packed at gk 40..45)
            acc0 = MFMA16(F0h[0], b0, bia0);
            acc0 = MFMA16(F0h[1], b1, acc0);
        }
        if (a1) {
            acc1 = MFMA16(F1h[0], b0, bia1);
            acc1 = MFMA16(F1h[1], b1, acc1);
            acc1 = MFMA16(F1h[2], b2, acc1);
        }
        if (a2) {
            acc2 = MFMA16(F2h[0], b1, bia2);
            acc2 = MFMA16(F2h[1], b2, acc2);
            acc2 = MFMA16(F2h[2], b3, acc2);
        }

        float ig0, v1_0, r1_0, ig1, v1_1, r1_1, ig2, v1_2, r1_2;
        // fs0 = v1 (hi-valid); fs1 = r1 (lo-valid); fs2 = v1 (hi-valid — c2's
        // only consumer th2->h2 is hi-only; lo garbage bounded, NaN-free).
        if (a0) { stage1(acc0, ig0, v1_0, r1_0); c0 = v1_0 * c0 + ig0; }
        if (a1) { stage1(acc1, ig1, v1_1, r1_1); c1 = r1_1 * c1 + ig1; }
        if (a2) { stage1(acc2, ig2, v1_2, r1_2); c2 = v1_2 * c2 + ig2; }

        // packed th: hi lanes tanh(c0), lo lanes tanh(c1) -> thA; tanh(c2)
        // hi-valid -> th2. Pre-scale muls and 1+e adds packed (v_pk_*_f32).
        float inC = hiL ? c0 : c1;
        f32x2 cc  = {inC, c2};
        f32x2 sc2 = cc * nl2e2;                     // packed * -2log2e
        f32x2 ex2 = {fast_exp2(sc2[0]), fast_exp2(sc2[1])};
        f32x2 dd2 = ex2 + one2;                     // packed 1+e
        float thA = 2.f * fast_rcp(dd2[0]) - 1.f;
        float th2 = 2.f * fast_rcp(dd2[1]) - 1.f;
        float thB = dpp_mov_ror8(thA);

        // h writes: single hi-lane region, single fp16 (cols 8-15 stay zero)
        if (hiL) {
            if (a0) Q[iH0] = (_Float16)(r1_0 * thA);  // L1 reads it here too
            if (a1) Q[iH1] = (_Float16)(r1_1 * thB);
            if (a2) {
                float h = r1_2 * th2;
                Q[iH2] = (_Float16)h;
                sY[((k - 2) & 7) * (HID * BT) + u * BT + n] = h * wov;
            }
        }
        if (xact) {   // stage x(k+1); clamped load, harmless past-end store
            Q[ixi] = (_Float16)xr;
            int kc = (k + 2 < T_LEN) ? (k + 2) : (T_LEN - 1);
            xr = xbl[(size_t)kc * 6];
        }
        // flush group (k-8..k-5): slots disjoint from this interval's write slot
        if ((k & 3) == 0 && k >= 8 && tid < 128) flushY(k - 8);
        __syncthreads();
    };

    // pipeline fill
    interval(sBF,         sBF + PARSZ, 0, true, false, false);
    interval(sBF + PARSZ, sBF,         1, true, true,  false);
    // steady state: k = 2..511, parity-unrolled x2
    for (int k = 2; k < T_LEN; k += 2) {
        interval(sBF,         sBF + PARSZ, k,     true, true, true);
        interval(sBF + PARSZ, sBF,         k + 1, true, true, true);
    }
    // pipeline drain (k=512 even -> reads parity 0)
    interval(sBF,         sBF + PARSZ, T_LEN,     false, true,  true);
    interval(sBF + PARSZ, sBF,         T_LEN + 1, false, false, true);
    // tail flush: t = 508..511 (barrier at end of last interval orders sY)
    if (tid < 128) flushY(T_LEN - 4);
}

extern "C" void kernel_launch(void* const* d_in, const int* in_sizes, int n_in,
                              void* d_out, int out_size, void* d_ws, size_t ws_size,
                              hipStream_t stream) {
    const float* x    = (const float*)d_in[0];
    const float* Wih0 = (const float*)d_in[1];
    const float* Whh0 = (const float*)d_in[2];
    const float* bih0 = (const float*)d_in[3];
    const float* bhh0 = (const float*)d_in[4];
    const float* Wih1 = (const float*)d_in[5];
    const float* Whh1 = (const float*)d_in[6];
    const float* bih1 = (const float*)d_in[7];
    const float* bhh1 = (const float*)d_in[8];
    const float* Wih2 = (const float*)d_in[9];
    const float* Whh2 = (const float*)d_in[10];
    const float* bih2 = (const float*)d_in[11];
    const float* bhh2 = (const float*)d_in[12];
    const float* Wout = (const float*)d_in[13];
    const float* bout = (const float*)d_in[14];

    lstm_fused<<<dim3(2048 / BT), dim3(NTH), 0, stream>>>(
        x, Wih0, Whh0, bih0, bhh0, Wih1, Whh1, bih1, bhh1,
        Wih2, Whh2, bih2, bhh2, Wout, bout, (float*)d_out);
}

// Round 12
// 420.175 us; speedup vs baseline: 1.0148x; 1.0148x over previous
//
#include <hip/hip_runtime.h>

#define T_LEN 512
#define HID   40
#define BT    8        // sequences per block -> grid 256 = 1 block/CU
#define NTH   640      // 10 waves; wave w owns units u = 4w..4w+3 (all 4 gates)

typedef _Float16 f16x8 __attribute__((ext_vector_type(8)));
typedef float    f32x4 __attribute__((ext_vector_type(4)));

// Unified B-buffer per parity: ONE chunked K-axis
//   [h0: gk 0..39 | x: 40..45 | h1: 46..85 | h2: 86..125 | pad: 126..127]
// = 128 chunks x 16 cols. Cols 0-7 = the 8 sequences; cols 8-15 are ZERO.
// All three gemms read phase-aligned 32-gk windows r0..r3 (4 x ds_read_b128).
// A-side: fp16 hi only. MFMA chains stay D=C chained (rounds 1/7: splitting
// a chain adds full MFMA->VALU hazard windows; C-accumulation is near-free).
// MFMA count 8 is the window floor (ceil(46/32)+ceil(80/32)+ceil(80/32));
// trans count 8 evals is the lane-pair floor; 1 barrier/timestep structural.
// Round-11's f32x2 packing regressed (v_pk operand-pairing moves outweigh
// dual-issue); this is the round-10 form — the measured optimum.
#define PARSZ 2048     // fp16 per parity (256 chunks * 8); 2 parities = 8 KB

#define NLOG2E  (-1.4426950408889634f)   // -log2(e): sigmoid-gate pre-scale
#define N2LOG2E (-2.8853900817779268f)   // -2*log2(e): tanh-gate pre-scale

__device__ __forceinline__ float fast_rcp(float v)  { return __builtin_amdgcn_rcpf(v); }
__device__ __forceinline__ float fast_exp2(float v) { return __builtin_amdgcn_exp2f(v); }

__device__ __forceinline__ float dpp_add_xor1(float x) {
    return x + __int_as_float(__builtin_amdgcn_update_dpp(
                   0, __float_as_int(x), 0xB1, 0xF, 0xF, true));
}
__device__ __forceinline__ float dpp_add_xor2(float x) {
    return x + __int_as_float(__builtin_amdgcn_update_dpp(
                   0, __float_as_int(x), 0x4E, 0xF, 0xF, true));
}
// row_ror:8 — lane n receives lane (n+8)%16 of its 16-lane row. Pure VALU.
__device__ __forceinline__ float dpp_mov_ror8(float x) {
    return __int_as_float(__builtin_amdgcn_update_dpp(
               0, __float_as_int(x), 0x128, 0xF, 0xF, true));
}
// masked ror8-select: lanes 0-7 of each row keep `keep`; lanes 8-15 receive
// `src` from lane (n+8)%16 (their hi partner). One v_mov_b32_dpp.
__device__ __forceinline__ float dpp_sel_ror8(float keep, float src) {
    return __int_as_float(__builtin_amdgcn_update_dpp(
               __float_as_int(keep), __float_as_int(src), 0x128, 0xF, 0xC, false));
}

// element index for (global-k, col): chunk = (gk/32)*64 + ((gk%32)/8)*16 + col
__device__ __forceinline__ int bidx(int gk, int col) {
    return (((gk >> 5) * 64) + (((gk >> 3) & 3) * 16) + col) * 8 + (gk & 7);
}

#define MFMA16(A, B, C) __builtin_amdgcn_mfma_f32_16x16x32_f16((A), (B), (C), 0, 0, 0)

__global__ __launch_bounds__(NTH, 1) void lstm_fused(
    const float* __restrict__ x,
    const float* __restrict__ Wih0, const float* __restrict__ Whh0,
    const float* __restrict__ bih0, const float* __restrict__ bhh0,
    const float* __restrict__ Wih1, const float* __restrict__ Whh1,
    const float* __restrict__ bih1, const float* __restrict__ bhh1,
    const float* __restrict__ Wih2, const float* __restrict__ Whh2,
    const float* __restrict__ bih2, const float* __restrict__ bhh2,
    const float* __restrict__ Wout, const float* __restrict__ bout,
    float* __restrict__ out) {
    __shared__ __attribute__((aligned(16))) _Float16 sBF[2 * PARSZ];   // 8 KB
    __shared__ __attribute__((aligned(16))) float    sY[8 * HID * BT]; // 10 KB

    const int  tid  = threadIdx.x;
    const int  lane = tid & 63;
    const int  w    = tid >> 6;       // wave id = u-tile
    const int  n    = lane & 15;      // B/D column (seq b when n<8; n>=8 helper)
    const int  quad = lane >> 4;
    const int  u    = w * 4 + quad;   // hidden unit this lane owns (cell update)
    const int  seq0 = blockIdx.x * BT;
    const bool hiL  = (n < 8);        // hi-half lane?

    // ---- A-fragments: gate-permuted rows (j = (r%4)*40 + w*4 + r/4), fp16 hi,
    // pre-scaled (sigmoid x -log2e, tanh x -2log2e). One frag per
    // (gemm, window): L0 uses {r0,r1} (x folded into r1), L1 {r0,r1,r2},
    // L2 {r1,r2,r3}.
    const int   ja  = (n & 3) * 40 + w * 4 + (n >> 2);
    const float sca = ((n & 3) == 2) ? N2LOG2E : NLOG2E;
    f16x8 F0h[2], F1h[3], F2h[3];
#pragma unroll
    for (int jj = 0; jj < 8; ++jj) {
        int gk0 = quad * 8 + jj;        // r0 window: gk 0..31
        int gk1 = 32 + gk0;             // r1: gk 32..63
        int gk2 = 64 + gk0;             // r2: gk 64..95
        int gk3 = 96 + gk0;             // r3: gk 96..127
        float v;
        // L0 = Whh0*h0 + Wih0*x : support gk 0..39 (h0) and 40..45 (x)
        v = Whh0[ja * 40 + gk0] * sca;
        F0h[0][jj] = (_Float16)v;
        v = (gk1 < 40) ? Whh0[ja * 40 + gk1] * sca
          : ((gk1 < 46) ? Wih0[ja * 6 + (gk1 - 40)] * sca : 0.f);
        F0h[1][jj] = (_Float16)v;
        // L1 = Wih1*h0 + Whh1*h1 : support gk 0..39 (h0) and 46..85 (h1)
        v = Wih1[ja * 40 + gk0] * sca;
        F1h[0][jj] = (_Float16)v;
        v = (gk1 < 40) ? Wih1[ja * 40 + gk1] * sca
          : ((gk1 >= 46) ? Whh1[ja * 40 + (gk1 - 46)] * sca : 0.f);
        F1h[1][jj] = (_Float16)v;
        v = (gk2 < 86) ? Whh1[ja * 40 + (gk2 - 46)] * sca : 0.f;
        F1h[2][jj] = (_Float16)v;
        // L2 = Wih2*h1 + Whh2*h2 : support gk 46..85 (h1) and 86..125 (h2)
        v = (gk1 >= 46) ? Wih2[ja * 40 + (gk1 - 46)] * sca : 0.f;
        F2h[0][jj] = (_Float16)v;
        v = ((gk2 < 86) ? Wih2[ja * 40 + (gk2 - 46)] : Whh2[ja * 40 + (gk2 - 86)]) * sca;
        F2h[1][jj] = (_Float16)v;
        v = (gk3 < 126) ? Whh2[ja * 40 + (gk3 - 86)] * sca : 0.f;
        F2h[2][jj] = (_Float16)v;
    }

    // biases: acc-init = scale*bias (single-column B: no hi+lo fold doubling)
    f32x4 bia0, bia1, bia2;
#pragma unroll
    for (int reg = 0; reg < 4; ++reg) {
        int   jr = reg * 40 + u;
        float sc = (reg == 2) ? N2LOG2E : NLOG2E;
        bia0[reg] = sc * (bih0[jr] + bhh0[jr]);
        bia1[reg] = sc * (bih1[jr] + bhh1[jr]);
        bia2[reg] = sc * (bih2[jr] + bhh2[jr]);
    }
    const float wov   = Wout[u];
    const float boutv = bout[0];
    // per-lane sigmoid/tanh affine constants: v0 = kA*e0 + kB
    // hi: 1*e0 + 0 = sigmoid   lo: 2*e0 - 1 = tanh  (exact coefficients)
    const float kA = hiL ? 1.f : 2.f;
    const float kB = hiL ? 0.f : -1.f;

    float c0 = 0.f, c1 = 0.f, c2 = 0.f;  // c0 valid on hi lanes, c1 on lo,
                                         // c2 on both (garbage halves bounded
                                         // and provably unconsumed)

    // ---- loop-invariant LDS indices (elems) ----
    const int rOff = lane * 8;           // shared-window read offset
    const int iH0  = bidx(u, n);         // h0 write (gk = u), hi lanes only
    const int iH1  = bidx(46 + u, n);    // h1 (gk = 46+u)
    const int iH2  = bidx(86 + u, n);    // h2 (gk = 86+u)

    // ---- x staging on wave 2 (x lives at gk 40..45, cols 0..7 only) ----
    const bool   xact = (tid >= 128 && tid < 176);
    const int    e    = tid - 128;
    const int    xs   = e / 6, xd = e % 6;
    const int    ixi  = bidx(40 + xd, xs);
    const float* xbl  = x + ((size_t)(seq0 + xs) * T_LEN) * 6 + xd;
    float        xr   = 0.f;
    if (xact) xr = xbl[0];  // x(0)

    // zero both parity banks (pads + cols 8-15 + unwritten regions stay zero)
    for (int i = tid; i < 2 * PARSZ / 8; i += NTH)
        *(float4*)&sBF[i * 8] = make_float4(0.f, 0.f, 0.f, 0.f);
    __syncthreads();
    if (xact) {
        sBF[ixi] = (_Float16)xr;   // x(0) -> parity 0
        xr = xbl[6];               // prefetch x(1)
    }
    __syncthreads();

    // stage1: bank-masked dpp gathers the partner's g/o accs onto lo lanes in
    // one instr each; affine kA/kB turns the sig/tanh divergence into one fma.
    // Returns: ig (valid both halves), v1 (hi = sig(f)), r1 = ror8(v1).
    auto stage1 = [&](f32x4 acc, float& ig, float& v1o, float& r1o) {
        float in0 = dpp_sel_ror8(acc[0], acc[2]);   // hi: i-acc  lo: g-acc
        float in1 = dpp_sel_ror8(acc[1], acc[3]);   // hi: f-acc  lo: o-acc
        float e0  = fast_rcp(1.f + fast_exp2(in0));
        float v0  = e0 * kA + kB;                   // hi: sig(i)  lo: tanh(g)
        float v1  = fast_rcp(1.f + fast_exp2(in1)); // hi: sig(f)  lo: sig(o)
        float r0  = dpp_mov_ror8(v0);
        ig  = v0 * r0;                              // sig(i)*tanh(g) both halves
        v1o = v1;
        r1o = dpp_mov_ror8(v1);
    };

    // lagged output flush on waves 0,1 (x duty stays on wave 2)
    auto flushY = [&](int t2g) {
        int q = tid, o = q >> 2, part = q & 3;
        int tt = o >> 3, bb = o & 7;
        int slot = (t2g + tt) & 7;
        float s = 0.f;
#pragma unroll
        for (int i2 = 0; i2 < 10; ++i2)
            s += sY[slot * (HID * BT) + (part * 10 + i2) * BT + bb];
        s = dpp_add_xor1(s);
        s = dpp_add_xor2(s);
        if (part == 0)
            out[(size_t)(seq0 + bb) * T_LEN + t2g + tt] = s + boutv;
    };

    // One pipeline interval k: L0(t=k), L1(t=k-1), L2(t=k-2). Reads P, writes Q,
    // ONE barrier. 4 shared b128 reads feed all three gemm chains (3x ILP).
    auto interval = [&](_Float16* __restrict__ P, _Float16* __restrict__ Q,
                        int k, bool a0, bool a1, bool a2) {
        f16x8 b0 = *(const f16x8*)(P + 0    + rOff);
        f16x8 b1 = *(const f16x8*)(P + 512  + rOff);
        f16x8 b2 = *(const f16x8*)(P + 1024 + rOff);
        f16x8 b3 = *(const f16x8*)(P + 1536 + rOff);

        f32x4 acc0, acc1, acc2;
        if (a0) {   // L0: K-support entirely in r0+r1 (x packed at gk 40..45)
            acc0 = MFMA16(F0h[0], b0, bia0);
            acc0 = MFMA16(F0h[1], b1, acc0);
        }
        if (a1) {
            acc1 = MFMA16(F1h[0], b0, bia1);
            acc1 = MFMA16(F1h[1], b1, acc1);
            acc1 = MFMA16(F1h[2], b2, acc1);
        }
        if (a2) {
            acc2 = MFMA16(F2h[0], b1, bia2);
            acc2 = MFMA16(F2h[1], b2, acc2);
            acc2 = MFMA16(F2h[2], b3, acc2);
        }

        float ig0, v1_0, r1_0, ig1, v1_1, r1_1, ig2, v1_2, r1_2;
        // fs0 = v1 (hi-valid, c0 consumed on hi only); fs1 = r1 (lo-valid);
        // fs2 needs the select (c2 consumed on both halves by th2).
        if (a0) { stage1(acc0, ig0, v1_0, r1_0); c0 = v1_0 * c0 + ig0; }
        if (a1) { stage1(acc1, ig1, v1_1, r1_1); c1 = r1_1 * c1 + ig1; }
        if (a2) { stage1(acc2, ig2, v1_2, r1_2);
                  float fs2 = hiL ? v1_2 : r1_2; c2 = fs2 * c2 + ig2; }

        // packed th: hi lanes tanh(c0), lo lanes tanh(c1), exchange to hi;
        // th2 on both halves (c2 duplicated). os* = r1_* (hi-only consumers).
        float inC = hiL ? c0 : c1;
        float thA = 2.f * fast_rcp(1.f + fast_exp2(inC * N2LOG2E)) - 1.f;
        float thB = dpp_mov_ror8(thA);
        float th2 = 2.f * fast_rcp(1.f + fast_exp2(c2 * N2LOG2E)) - 1.f;

        // h writes: hi lanes only, single fp16 (cols 8-15 stay zero)
        if (a0 && hiL) Q[iH0] = (_Float16)(r1_0 * thA);  // L1 reads it here too
        if (a1 && hiL) Q[iH1] = (_Float16)(r1_1 * thB);
        if (a2 && hiL) {
            float h = r1_2 * th2;
            Q[iH2] = (_Float16)h;
            sY[((k - 2) & 7) * (HID * BT) + u * BT + n] = h * wov;
        }
        if (xact) {   // stage x(k+1); clamped load, harmless past-end store
            Q[ixi] = (_Float16)xr;
            int kc = (k + 2 < T_LEN) ? (k + 2) : (T_LEN - 1);
            xr = xbl[(size_t)kc * 6];
        }
        // flush group (k-8..k-5): slots disjoint from this interval's write slot
        if ((k & 3) == 0 && k >= 8 && tid < 128) flushY(k - 8);
        __syncthreads();
    };

    // pipeline fill
    interval(sBF,         sBF + PARSZ, 0, true, false, false);
    interval(sBF + PARSZ, sBF,         1, true, true,  false);
    // steady state: k = 2..511, parity-unrolled x2
    for (int k = 2; k < T_LEN; k += 2) {
        interval(sBF,         sBF + PARSZ, k,     true, true, true);
        interval(sBF + PARSZ, sBF,         k + 1, true, true, true);
    }
    // pipeline drain (k=512 even -> reads parity 0)
    interval(sBF,         sBF + PARSZ, T_LEN,     false, true,  true);
    interval(sBF + PARSZ, sBF,         T_LEN + 1, false, false, true);
    // tail flush: t = 508..511 (barrier at end of last interval orders sY)
    if (tid < 128) flushY(T_LEN - 4);
}

extern "C" void kernel_launch(void* const* d_in, const int* in_sizes, int n_in,
                              void* d_out, int out_size, void* d_ws, size_t ws_size,
                              hipStream_t stream) {
    const float* x    = (const float*)d_in[0];
    const float* Wih0 = (const float*)d_in[1];
    const float* Whh0 = (const float*)d_in[2];
    const float* bih0 = (const float*)d_in[3];
    const float* bhh0 = (const float*)d_in[4];
    const float* Wih1 = (const float*)d_in[5];
    const float* Whh1 = (const float*)d_in[6];
    const float* bih1 = (const float*)d_in[7];
    const float* bhh1 = (const float*)d_in[8];
    const float* Wih2 = (const float*)d_in[9];
    const float* Whh2 = (const float*)d_in[10];
    const float* bih2 = (const float*)d_in[11];
    const float* bhh2 = (const float*)d_in[12];
    const float* Wout = (const float*)d_in[13];
    const float* bout = (const float*)d_in[14];

    lstm_fused<<<dim3(2048 / BT), dim3(NTH), 0, stream>>>(
        x, Wih0, Whh0, bih0, bhh0, Wih1, Whh1, bih1, bhh1,
        Wih2, Whh2, bih2, bhh2, Wout, bout, (float*)d_out);
}